// Round 2
// baseline (249.558 us; speedup 1.0000x reference)
//
#include <hip/hip_runtime.h>
#include <stdint.h>
#include <math.h>

// ---------------- problem constants ----------------
namespace {
constexpr int Bn = 512, Dn = 128, Wn = 30, Kn = 5;
constexpr int HWn = 900;  // 30*30

// workspace float offsets (total ~0.93M floats = 3.7 MB)
constexpr size_t OFF_A    = 0;                            // Kn*Dn = 640
constexpr size_t OFF_SA   = OFF_A + (size_t)Kn * Dn;      // 5 (pad 8)
constexpr size_t OFF_C0   = OFF_SA + 8;                   // 5 (pad 8)
constexpr size_t OFF_MEAN = OFF_C0 + 8;                   // Bn*HWn
constexpr size_t OFF_RSTD = OFF_MEAN + (size_t)Bn * HWn;  // Bn*HWn
constexpr size_t OFF_C    = OFF_RSTD + (size_t)Bn * HWn;  // Bn*Kn
constexpr size_t OFF_ENT  = OFF_C + (size_t)Bn * Kn;      // Bn*Kn

// output float offsets (centroids, attention_maps, stop_logits concatenated)
// NOTE: the OUT_ATTN region doubles as scratch: k_base writes base scores
// there, k_loop reads them and overwrites in-place with the attention maps.
constexpr size_t OUT_CENT = 0;
constexpr size_t OUT_ATTN = (size_t)Bn * Kn * 2;               // 5120
constexpr size_t OUT_STOP = OUT_ATTN + (size_t)Bn * Kn * HWn;  // 2309120
}  // namespace

struct FoldedKeys { uint32_t k1[5]; uint32_t k2[5]; };

// ---------------- threefry2x32 (JAX-compatible, 20 rounds) ----------------
__host__ __device__ static inline uint32_t rotl32(uint32_t x, int d) {
  return (x << d) | (x >> (32 - d));
}

__host__ __device__ static inline void threefry2x32(uint32_t k1, uint32_t k2,
                                                    uint32_t& x0, uint32_t& x1) {
  uint32_t k3 = k1 ^ k2 ^ 0x1BD11BDAu;
  x0 += k1; x1 += k2;
#define TF_R(rot) { x0 += x1; x1 = rotl32(x1, rot); x1 ^= x0; }
  TF_R(13) TF_R(15) TF_R(26) TF_R(6)   x0 += k2; x1 += k3 + 1u;
  TF_R(17) TF_R(29) TF_R(16) TF_R(24)  x0 += k3; x1 += k1 + 2u;
  TF_R(13) TF_R(15) TF_R(26) TF_R(6)   x0 += k1; x1 += k2 + 3u;
  TF_R(17) TF_R(29) TF_R(16) TF_R(24)  x0 += k2; x1 += k3 + 4u;
  TF_R(13) TF_R(15) TF_R(26) TF_R(6)   x0 += k3; x1 += k1 + 5u;
#undef TF_R
}

// ---------------- reduction helpers ----------------
__device__ static inline float wsum(float v) {
#pragma unroll
  for (int o = 32; o; o >>= 1) v += __shfl_xor(v, o, 64);
  return v;
}
__device__ static inline float wmaxr(float v) {
#pragma unroll
  for (int o = 32; o; o >>= 1) v = fmaxf(v, __shfl_xor(v, o, 64));
  return v;
}
__device__ static inline float bsum4(float v, float* scr) {  // 256-thread block
  v = wsum(v);
  if ((threadIdx.x & 63) == 0) scr[threadIdx.x >> 6] = v;
  __syncthreads();
  float r = scr[0] + scr[1] + scr[2] + scr[3];
  __syncthreads();
  return r;
}
__device__ static inline float bmax4(float v, float* scr) {
  v = wmaxr(v);
  if ((threadIdx.x & 63) == 0) scr[threadIdx.x >> 6] = v;
  __syncthreads();
  float r = fmaxf(fmaxf(scr[0], scr[1]), fmaxf(scr[2], scr[3]));
  __syncthreads();
  return r;
}
__device__ static inline float bsum2(float v, float* scr) {  // 128-thread block
  v = wsum(v);
  if ((threadIdx.x & 63) == 0) scr[threadIdx.x >> 6] = v;
  __syncthreads();
  float r = scr[0] + scr[1];
  __syncthreads();
  return r;
}

// ---------------- kernel 0: per-query constants ----------------
// q = LN(clue)@wq.T+bq ; qk = q@wk ; A = fn_g*qk ; SA = sum A ; C0 = fn_b.qk + q.bk
__global__ __launch_bounds__(128) void k_prep(
    const float* __restrict__ clue, const float* __restrict__ wq,
    const float* __restrict__ bq, const float* __restrict__ wk,
    const float* __restrict__ bk, const float* __restrict__ qn_g,
    const float* __restrict__ qn_b, const float* __restrict__ fn_g,
    const float* __restrict__ fn_b, float* __restrict__ ws) {
  __shared__ float scr[2];
  __shared__ float lnc[Dn], qrow[Dn], qkrow[Dn];
  const int k = blockIdx.x, t = threadIdx.x;
  float xv = clue[(size_t)k * Dn + t];
  float m = bsum2(xv, scr) * (1.0f / Dn);
  float dd = xv - m;
  float var = bsum2(dd * dd, scr) * (1.0f / Dn);
  float r = 1.0f / sqrtf(var + 1e-5f);
  lnc[t] = dd * r * qn_g[t] + qn_b[t];
  __syncthreads();
  {
    float acc = bq[t];
    const float* wr = wq + (size_t)t * Dn;
    for (int e = 0; e < Dn; ++e) acc += lnc[e] * wr[e];
    qrow[t] = acc;
  }
  __syncthreads();
  {
    float acc = 0.f;
    for (int d = 0; d < Dn; ++d) acc += qrow[d] * wk[(size_t)d * Dn + t];
    qkrow[t] = acc;
    ws[OFF_A + (size_t)k * Dn + t] = fn_g[t] * acc;
  }
  __syncthreads();
  float sa = bsum2(fn_g[t] * qkrow[t], scr);
  float c0 = bsum2(fn_b[t] * qkrow[t] + qrow[t] * bk[t], scr);
  if (t == 0) {
    ws[OFF_SA + k] = sa;
    ws[OFF_C0 + k] = c0;
  }
}

// ---------------- kernel 1: fused LN-stats + base scores ----------------
// one streaming pass over features (B, D, HW); thread = one pixel n.
// base scores land in the OUT_ATTN region (scratch, overwritten by k_loop).
__global__ __launch_bounds__(256) void k_base(const float* __restrict__ x,
                                              float* __restrict__ ws,
                                              float* out) {
  const int b = blockIdx.y;
  const int n = blockIdx.x * 256 + threadIdx.x;
  if (n >= HWn) return;
  const float* __restrict__ A = ws + OFF_A;
  const float* xp = x + (size_t)b * Dn * HWn + n;
  float sum = 0.f, ssq = 0.f;
  float sd0 = 0, sd1 = 0, sd2 = 0, sd3 = 0, sd4 = 0;
  for (int e = 0; e < Dn; ++e) {
    float v = xp[(size_t)e * HWn];
    sum += v; ssq += v * v;
    sd0 += v * A[e];
    sd1 += v * A[Dn + e];
    sd2 += v * A[2 * Dn + e];
    sd3 += v * A[3 * Dn + e];
    sd4 += v * A[4 * Dn + e];
  }
  const float m = sum * (1.0f / Dn);
  const float var = ssq * (1.0f / Dn) - m * m;
  const float r = 1.0f / sqrtf(var + 1e-5f);
  ws[OFF_MEAN + (size_t)b * HWn + n] = m;
  ws[OFF_RSTD + (size_t)b * HWn + n] = r;
  const float sd[5] = {sd0, sd1, sd2, sd3, sd4};
  const float* SA = ws + OFF_SA;
  const float* C0 = ws + OFF_C0;
#pragma unroll
  for (int k = 0; k < Kn; ++k) {
    float basev = (r * (sd[k] - m * SA[k]) + C0[k]) / sqrtf((float)Dn);
    out[OUT_ATTN + ((size_t)(b * Kn + k)) * HWn + n] = basev;
  }
}

// ---------------- kernel 2: sequential gumbel-softmax loop (per batch) ------
// JAX partitionable threefry bits: per element j, counter=(0,j),
// bits = out0 ^ out1.
__global__ __launch_bounds__(256) void k_loop(float* __restrict__ ws,
                                              float* out, FoldedKeys keys) {
  __shared__ float scr[4];
  const int b = blockIdx.x, t = threadIdx.x;
  float mr[4], rr[4], cum[4];
  int nn[4];
  bool vv[4];
#pragma unroll
  for (int i = 0; i < 4; ++i) {
    int n = t + i * 256;
    nn[i] = n; vv[i] = (n < HWn);
    float m = 0.f, r = 0.f;
    if (vv[i]) {
      m = ws[OFF_MEAN + (size_t)b * HWn + n];
      r = ws[OFF_RSTD + (size_t)b * HWn + n];
    }
    mr[i] = m * r; rr[i] = r; cum[i] = 1.0f;
  }
  for (int k = 0; k < Kn; ++k) {
    const uint32_t fk1 = keys.k1[k], fk2 = keys.k2[k];
    float noisy[4];
#pragma unroll
    for (int i = 0; i < 4; ++i) {
      noisy[i] = -1e30f;
      if (vv[i]) {
        float s = out[OUT_ATTN + ((size_t)(b * Kn + k)) * HWn + nn[i]] + logf(cum[i]);
        s = fminf(fmaxf(s, -50.f), 50.f);
        uint32_t j = (uint32_t)(b * HWn + nn[i]);
        uint32_t x0 = 0u, x1 = j;          // counter = (hi32(j), lo32(j))
        threefry2x32(fk1, fk2, x0, x1);
        uint32_t bits = x0 ^ x1;           // partitionable 32-bit draw
        float u = __uint_as_float((bits >> 9) | 0x3f800000u) - 1.0f;
        u = fmaxf(u, 1e-10f);
        float g = -logf(-logf(u));
        noisy[i] = fminf(fmaxf(s + g, -50.f), 50.f);
      }
    }
    float lm = fmaxf(fmaxf(noisy[0], noisy[1]), fmaxf(noisy[2], noisy[3]));
    const float M = bmax4(lm, scr);
    float p[4]; float ls = 0.f;
#pragma unroll
    for (int i = 0; i < 4; ++i) {
      p[i] = vv[i] ? expf(noisy[i] - M) : 0.f;
      ls += p[i];
    }
    const float Z = bsum4(ls, scr);
    float cr = 0.f, cc = 0.f, ea = 0.f, ca = 0.f;
#pragma unroll
    for (int i = 0; i < 4; ++i) {
      if (vv[i]) {
        float a = p[i] / Z;
        out[OUT_ATTN + ((size_t)(b * Kn + k)) * HWn + nn[i]] = a;  // overwrite base
        cr += a * (float)(nn[i] / Wn);
        cc += a * (float)(nn[i] % Wn);
        float ac = fmaxf(a, 1e-10f);
        ea += ac * logf(ac);
        ca += a * mr[i];
        cum[i] = fmaxf(cum[i] * (1.0f - 0.9f * a), 1e-6f);
      }
    }
    cr = bsum4(cr, scr);
    cc = bsum4(cc, scr);
    ea = bsum4(ea, scr);
    ca = bsum4(ca, scr);
    if (t == 0) {
      out[OUT_CENT + ((size_t)(b * Kn + k)) * 2 + 0] = cr;
      out[OUT_CENT + ((size_t)(b * Kn + k)) * 2 + 1] = cc;
      ws[OFF_C + (size_t)b * Kn + k] = ca;
      ws[OFF_ENT + (size_t)b * Kn + k] = -ea / logf(900.0f);
    }
  }
}

// ---------------- kernel 3: attended features + MLP + stop logits -----------
__global__ __launch_bounds__(256) void k_attend(
    const float* __restrict__ x, const float* __restrict__ ws,
    const float* __restrict__ wv, const float* __restrict__ bv,
    const float* __restrict__ sw1, const float* __restrict__ sb1,
    const float* __restrict__ sw2, const float* __restrict__ sb2,
    const float* __restrict__ fn_g, const float* __restrict__ fn_b,
    float* out) {
  __shared__ float wl[Kn * HWn];   // 4500 floats: w = attn*rstd for this b
  __shared__ float dots[Kn * Dn];  // raw weighted sums over n
  __shared__ float af[Kn * Dn];    // attn-weighted normalized features
  __shared__ float att[Kn * Dn];   // after wv projection
  __shared__ float hbuf[Kn * 64];  // MLP hidden
  const int b = blockIdx.x, t = threadIdx.x;
  for (int i = t; i < Kn * HWn; i += 256) {
    int n = i % HWn;
    wl[i] = out[OUT_ATTN + (size_t)b * (Kn * HWn) + i] *
            ws[OFF_RSTD + (size_t)b * HWn + n];
  }
  __syncthreads();
  const int lane = t & 63, wid = t >> 6;
  for (int d = wid; d < Dn; d += 4) {
    const float* xp = x + ((size_t)b * Dn + d) * HWn;
    float a0 = 0, a1 = 0, a2 = 0, a3 = 0, a4 = 0;
    for (int n = lane; n < HWn; n += 64) {
      float v = xp[n];
      a0 += v * wl[n];
      a1 += v * wl[HWn + n];
      a2 += v * wl[2 * HWn + n];
      a3 += v * wl[3 * HWn + n];
      a4 += v * wl[4 * HWn + n];
    }
    a0 = wsum(a0); a1 = wsum(a1); a2 = wsum(a2); a3 = wsum(a3); a4 = wsum(a4);
    if (lane == 0) {
      dots[0 * Dn + d] = a0; dots[1 * Dn + d] = a1; dots[2 * Dn + d] = a2;
      dots[3 * Dn + d] = a3; dots[4 * Dn + d] = a4;
    }
  }
  __syncthreads();
  for (int i = t; i < Kn * Dn; i += 256) {
    int k = i >> 7, e = i & 127;
    af[i] = fn_g[e] * (dots[i] - ws[OFF_C + (size_t)b * Kn + k]) + fn_b[e];
  }
  __syncthreads();
  for (int i = t; i < Kn * Dn; i += 256) {
    int k = i >> 7, d2 = i & 127;
    const float* wr = wv + (size_t)d2 * Dn;
    float s = bv[d2];
    for (int e = 0; e < Dn; ++e) s += wr[e] * af[(k << 7) + e];
    att[i] = s;
  }
  __syncthreads();
  for (int i = t; i < Kn * 64; i += 256) {
    int k = i >> 6, j = i & 63;
    const float* sr = sw1 + (size_t)j * (Dn + 1);
    float s = sb1[j];
    for (int e = 0; e < Dn; ++e) s += sr[e] * att[(k << 7) + e];
    s += ws[OFF_ENT + (size_t)b * Kn + k] * sr[Dn];
    // exact GELU: x * (erf(x/sqrt(2)) + 1) / 2
    hbuf[i] = s * (erff(s / 1.41421356237309515f) + 1.0f) * 0.5f;
  }
  __syncthreads();
  if (t < Kn) {
    float s = sb2[0];
    for (int j = 0; j < 64; ++j) s += hbuf[(t << 6) + j] * sw2[j];
    out[OUT_STOP + (size_t)b * Kn + t] = s;
  }
}

// ---------------- launch ----------------
extern "C" void kernel_launch(void* const* d_in, const int* in_sizes, int n_in,
                              void* d_out, int out_size, void* d_ws, size_t ws_size,
                              hipStream_t stream) {
  (void)in_sizes; (void)n_in; (void)out_size; (void)ws_size;
  const float* features = (const float*)d_in[0];
  const float* clue     = (const float*)d_in[1];
  const float* wq       = (const float*)d_in[2];
  const float* bq       = (const float*)d_in[3];
  const float* wk       = (const float*)d_in[4];
  const float* bk       = (const float*)d_in[5];
  const float* wv       = (const float*)d_in[6];
  const float* bv       = (const float*)d_in[7];
  const float* sw1      = (const float*)d_in[8];
  const float* sb1      = (const float*)d_in[9];
  const float* sw2      = (const float*)d_in[10];
  const float* sb2      = (const float*)d_in[11];
  const float* qn_g     = (const float*)d_in[12];
  const float* qn_b     = (const float*)d_in[13];
  const float* fn_g     = (const float*)d_in[14];
  const float* fn_b     = (const float*)d_in[15];
  float* ws  = (float*)d_ws;
  float* out = (float*)d_out;

  // fold_in(key(42), k) on host: key(42) == [0, 42]; fold data == [0, k];
  // new key = full threefry output pair (unchanged by partitionable flag).
  FoldedKeys fk;
  for (int k = 0; k < Kn; ++k) {
    uint32_t x0 = 0u, x1 = (uint32_t)k;
    threefry2x32(0u, 42u, x0, x1);
    fk.k1[k] = x0; fk.k2[k] = x1;
  }

  hipLaunchKernelGGL(k_prep, dim3(Kn), dim3(128), 0, stream,
                     clue, wq, bq, wk, bk, qn_g, qn_b, fn_g, fn_b, ws);
  hipLaunchKernelGGL(k_base, dim3(4, Bn), dim3(256), 0, stream, features, ws, out);
  hipLaunchKernelGGL(k_loop, dim3(Bn), dim3(256), 0, stream, ws, out, fk);
  hipLaunchKernelGGL(k_attend, dim3(Bn), dim3(256), 0, stream,
                     features, ws, wv, bv, sw1, sb1, sw2, sb2, fn_g, fn_b, out);
}

// Round 3
// 168.239 us; speedup vs baseline: 1.4834x; 1.4834x over previous
//
#include <hip/hip_runtime.h>
#include <stdint.h>
#include <math.h>

// ---------------- problem constants ----------------
namespace {
constexpr int Bn = 512, Dn = 128, Wn = 30, Kn = 5;
constexpr int HWn = 900;  // 30*30

// workspace float offsets (total ~5 MB)
constexpr size_t OFF_A    = 0;                            // Kn*Dn = 640
constexpr size_t OFF_SA   = OFF_A + (size_t)Kn * Dn;      // 5 (pad 8)
constexpr size_t OFF_C0   = OFF_SA + 8;                   // 5 (pad 8)
constexpr size_t OFF_MEAN = OFF_C0 + 8;                   // Bn*HWn
constexpr size_t OFF_RSTD = OFF_MEAN + (size_t)Bn * HWn;  // Bn*HWn
constexpr size_t OFF_C    = OFF_RSTD + (size_t)Bn * HWn;  // Bn*Kn
constexpr size_t OFF_ENT  = OFF_C + (size_t)Bn * Kn;      // Bn*Kn
constexpr size_t OFF_DOTS = OFF_ENT + (size_t)Bn * Kn;    // Bn*Kn*Dn

// output float offsets (centroids, attention_maps, stop_logits concatenated)
// NOTE: the OUT_ATTN region doubles as scratch: k_base writes base scores
// there, k_loop reads them and overwrites in-place with the attention maps.
constexpr size_t OUT_CENT = 0;
constexpr size_t OUT_ATTN = (size_t)Bn * Kn * 2;               // 5120
constexpr size_t OUT_STOP = OUT_ATTN + (size_t)Bn * Kn * HWn;  // 2309120
}  // namespace

struct FoldedKeys { uint32_t k1[5]; uint32_t k2[5]; };

// ---------------- threefry2x32 (JAX-compatible, 20 rounds) ----------------
__host__ __device__ static inline uint32_t rotl32(uint32_t x, int d) {
  return (x << d) | (x >> (32 - d));
}

__host__ __device__ static inline void threefry2x32(uint32_t k1, uint32_t k2,
                                                    uint32_t& x0, uint32_t& x1) {
  uint32_t k3 = k1 ^ k2 ^ 0x1BD11BDAu;
  x0 += k1; x1 += k2;
#define TF_R(rot) { x0 += x1; x1 = rotl32(x1, rot); x1 ^= x0; }
  TF_R(13) TF_R(15) TF_R(26) TF_R(6)   x0 += k2; x1 += k3 + 1u;
  TF_R(17) TF_R(29) TF_R(16) TF_R(24)  x0 += k3; x1 += k1 + 2u;
  TF_R(13) TF_R(15) TF_R(26) TF_R(6)   x0 += k1; x1 += k2 + 3u;
  TF_R(17) TF_R(29) TF_R(16) TF_R(24)  x0 += k2; x1 += k3 + 4u;
  TF_R(13) TF_R(15) TF_R(26) TF_R(6)   x0 += k3; x1 += k1 + 5u;
#undef TF_R
}

// ---------------- reduction helpers ----------------
__device__ static inline float wsum(float v) {
#pragma unroll
  for (int o = 32; o; o >>= 1) v += __shfl_xor(v, o, 64);
  return v;
}
__device__ static inline float wmaxr(float v) {
#pragma unroll
  for (int o = 32; o; o >>= 1) v = fmaxf(v, __shfl_xor(v, o, 64));
  return v;
}
__device__ static inline float bsum4(float v, float* scr) {  // 256-thread block
  v = wsum(v);
  if ((threadIdx.x & 63) == 0) scr[threadIdx.x >> 6] = v;
  __syncthreads();
  float r = scr[0] + scr[1] + scr[2] + scr[3];
  __syncthreads();
  return r;
}
__device__ static inline float bmax4(float v, float* scr) {
  v = wmaxr(v);
  if ((threadIdx.x & 63) == 0) scr[threadIdx.x >> 6] = v;
  __syncthreads();
  float r = fmaxf(fmaxf(scr[0], scr[1]), fmaxf(scr[2], scr[3]));
  __syncthreads();
  return r;
}
__device__ static inline float bsum2(float v, float* scr) {  // 128-thread block
  v = wsum(v);
  if ((threadIdx.x & 63) == 0) scr[threadIdx.x >> 6] = v;
  __syncthreads();
  float r = scr[0] + scr[1];
  __syncthreads();
  return r;
}

// ---------------- kernel 0: per-query constants ----------------
// q = LN(clue)@wq.T+bq ; qk = q@wk ; A = fn_g*qk ; SA = sum A ; C0 = fn_b.qk + q.bk
__global__ __launch_bounds__(128) void k_prep(
    const float* __restrict__ clue, const float* __restrict__ wq,
    const float* __restrict__ bq, const float* __restrict__ wk,
    const float* __restrict__ bk, const float* __restrict__ qn_g,
    const float* __restrict__ qn_b, const float* __restrict__ fn_g,
    const float* __restrict__ fn_b, float* __restrict__ ws) {
  __shared__ float scr[2];
  __shared__ float lnc[Dn], qrow[Dn], qkrow[Dn];
  const int k = blockIdx.x, t = threadIdx.x;
  float xv = clue[(size_t)k * Dn + t];
  float m = bsum2(xv, scr) * (1.0f / Dn);
  float dd = xv - m;
  float var = bsum2(dd * dd, scr) * (1.0f / Dn);
  float r = 1.0f / sqrtf(var + 1e-5f);
  lnc[t] = dd * r * qn_g[t] + qn_b[t];
  __syncthreads();
  {
    float acc = bq[t];
    const float* wr = wq + (size_t)t * Dn;
    for (int e = 0; e < Dn; ++e) acc += lnc[e] * wr[e];
    qrow[t] = acc;
  }
  __syncthreads();
  {
    float acc = 0.f;
    for (int d = 0; d < Dn; ++d) acc += qrow[d] * wk[(size_t)d * Dn + t];
    qkrow[t] = acc;
    ws[OFF_A + (size_t)k * Dn + t] = fn_g[t] * acc;
  }
  __syncthreads();
  float sa = bsum2(fn_g[t] * qkrow[t], scr);
  float c0 = bsum2(fn_b[t] * qkrow[t] + qrow[t] * bk[t], scr);
  if (t == 0) {
    ws[OFF_SA + k] = sa;
    ws[OFF_C0 + k] = c0;
  }
}

// ---------------- kernel 1: fused LN-stats + base scores ----------------
// one streaming pass over features (B, D, HW); thread = one pixel n.
// base scores land in the OUT_ATTN region (scratch, overwritten by k_loop).
__global__ __launch_bounds__(256) void k_base(const float* __restrict__ x,
                                              float* __restrict__ ws,
                                              float* out) {
  const int b = blockIdx.y;
  const int n = blockIdx.x * 256 + threadIdx.x;
  if (n >= HWn) return;
  const float* __restrict__ A = ws + OFF_A;
  const float* xp = x + (size_t)b * Dn * HWn + n;
  float sum = 0.f, ssq = 0.f;
  float sd0 = 0, sd1 = 0, sd2 = 0, sd3 = 0, sd4 = 0;
  for (int e = 0; e < Dn; ++e) {
    float v = xp[(size_t)e * HWn];
    sum += v; ssq += v * v;
    sd0 += v * A[e];
    sd1 += v * A[Dn + e];
    sd2 += v * A[2 * Dn + e];
    sd3 += v * A[3 * Dn + e];
    sd4 += v * A[4 * Dn + e];
  }
  const float m = sum * (1.0f / Dn);
  const float var = ssq * (1.0f / Dn) - m * m;
  const float r = 1.0f / sqrtf(var + 1e-5f);
  ws[OFF_MEAN + (size_t)b * HWn + n] = m;
  ws[OFF_RSTD + (size_t)b * HWn + n] = r;
  const float sd[5] = {sd0, sd1, sd2, sd3, sd4};
  const float* SA = ws + OFF_SA;
  const float* C0 = ws + OFF_C0;
#pragma unroll
  for (int k = 0; k < Kn; ++k) {
    float basev = (r * (sd[k] - m * SA[k]) + C0[k]) / sqrtf((float)Dn);
    out[OUT_ATTN + ((size_t)(b * Kn + k)) * HWn + n] = basev;
  }
}

// ---------------- kernel 2: sequential gumbel-softmax loop (per batch) ------
// JAX partitionable threefry bits: per element j, counter=(0,j),
// bits = out0 ^ out1.
__global__ __launch_bounds__(256) void k_loop(float* __restrict__ ws,
                                              float* out, FoldedKeys keys) {
  __shared__ float scr[4];
  const int b = blockIdx.x, t = threadIdx.x;
  float mr[4], rr[4], cum[4];
  int nn[4];
  bool vv[4];
#pragma unroll
  for (int i = 0; i < 4; ++i) {
    int n = t + i * 256;
    nn[i] = n; vv[i] = (n < HWn);
    float m = 0.f, r = 0.f;
    if (vv[i]) {
      m = ws[OFF_MEAN + (size_t)b * HWn + n];
      r = ws[OFF_RSTD + (size_t)b * HWn + n];
    }
    mr[i] = m * r; rr[i] = r; cum[i] = 1.0f;
  }
  for (int k = 0; k < Kn; ++k) {
    const uint32_t fk1 = keys.k1[k], fk2 = keys.k2[k];
    float noisy[4];
#pragma unroll
    for (int i = 0; i < 4; ++i) {
      noisy[i] = -1e30f;
      if (vv[i]) {
        float s = out[OUT_ATTN + ((size_t)(b * Kn + k)) * HWn + nn[i]] + logf(cum[i]);
        s = fminf(fmaxf(s, -50.f), 50.f);
        uint32_t j = (uint32_t)(b * HWn + nn[i]);
        uint32_t x0 = 0u, x1 = j;          // counter = (hi32(j), lo32(j))
        threefry2x32(fk1, fk2, x0, x1);
        uint32_t bits = x0 ^ x1;           // partitionable 32-bit draw
        float u = __uint_as_float((bits >> 9) | 0x3f800000u) - 1.0f;
        u = fmaxf(u, 1e-10f);
        float g = -logf(-logf(u));
        noisy[i] = fminf(fmaxf(s + g, -50.f), 50.f);
      }
    }
    float lm = fmaxf(fmaxf(noisy[0], noisy[1]), fmaxf(noisy[2], noisy[3]));
    const float M = bmax4(lm, scr);
    float p[4]; float ls = 0.f;
#pragma unroll
    for (int i = 0; i < 4; ++i) {
      p[i] = vv[i] ? expf(noisy[i] - M) : 0.f;
      ls += p[i];
    }
    const float Z = bsum4(ls, scr);
    float cr = 0.f, cc = 0.f, ea = 0.f, ca = 0.f;
#pragma unroll
    for (int i = 0; i < 4; ++i) {
      if (vv[i]) {
        float a = p[i] / Z;
        out[OUT_ATTN + ((size_t)(b * Kn + k)) * HWn + nn[i]] = a;  // overwrite base
        cr += a * (float)(nn[i] / Wn);
        cc += a * (float)(nn[i] % Wn);
        float ac = fmaxf(a, 1e-10f);
        ea += ac * logf(ac);
        ca += a * mr[i];
        cum[i] = fmaxf(cum[i] * (1.0f - 0.9f * a), 1e-6f);
      }
    }
    cr = bsum4(cr, scr);
    cc = bsum4(cc, scr);
    ea = bsum4(ea, scr);
    ca = bsum4(ca, scr);
    if (t == 0) {
      out[OUT_CENT + ((size_t)(b * Kn + k)) * 2 + 0] = cr;
      out[OUT_CENT + ((size_t)(b * Kn + k)) * 2 + 1] = cc;
      ws[OFF_C + (size_t)b * Kn + k] = ca;
      ws[OFF_ENT + (size_t)b * Kn + k] = -ea / logf(900.0f);
    }
  }
}

// ---------------- kernel 3: attended-feature dot products (streaming) -------
// grid (4, B): block = (32-channel chunk, batch). High occupancy version.
// dots[b,k,d] = sum_n x[b,d,n] * attn[b,k,n] * rstd[b,n]
__global__ __launch_bounds__(256) void k_dots(const float* __restrict__ x,
                                              float* __restrict__ ws,
                                              const float* __restrict__ out) {
  __shared__ float wl[Kn * HWn];  // 18000 B: attn*rstd for this b
  const int b = blockIdx.y, chunk = blockIdx.x;
  const int t = threadIdx.x;
  for (int i = t; i < Kn * HWn; i += 256) {
    int n = i % HWn;
    wl[i] = out[OUT_ATTN + (size_t)b * (Kn * HWn) + i] *
            ws[OFF_RSTD + (size_t)b * HWn + n];
  }
  __syncthreads();
  const int lane = t & 63, wid = t >> 6;
  const int d0 = chunk * 32 + wid * 8;  // this warp's 8 channels
  const float* xb = x + ((size_t)b * Dn + d0) * HWn;
  float acc[8][5];
#pragma unroll
  for (int j = 0; j < 8; ++j)
#pragma unroll
    for (int k = 0; k < Kn; ++k) acc[j][k] = 0.f;
  for (int n = lane; n < HWn; n += 64) {
    float w0 = wl[n], w1 = wl[HWn + n], w2 = wl[2 * HWn + n],
          w3 = wl[3 * HWn + n], w4 = wl[4 * HWn + n];
#pragma unroll
    for (int j = 0; j < 8; ++j) {
      float v = xb[(size_t)j * HWn + n];
      acc[j][0] += v * w0; acc[j][1] += v * w1; acc[j][2] += v * w2;
      acc[j][3] += v * w3; acc[j][4] += v * w4;
    }
  }
#pragma unroll
  for (int j = 0; j < 8; ++j)
#pragma unroll
    for (int k = 0; k < Kn; ++k) {
      float s = wsum(acc[j][k]);
      if (lane == 0)
        ws[OFF_DOTS + ((size_t)b * Kn + k) * Dn + d0 + j] = s;
    }
}

// ---------------- kernel 4: LN-combine + wv proj + MLP + stop logits --------
__global__ __launch_bounds__(256) void k_finish(
    const float* __restrict__ ws, const float* __restrict__ wv,
    const float* __restrict__ bv, const float* __restrict__ sw1,
    const float* __restrict__ sb1, const float* __restrict__ sw2,
    const float* __restrict__ sb2, const float* __restrict__ fn_g,
    const float* __restrict__ fn_b, float* out) {
  __shared__ float af[Kn * Dn];    // attn-weighted normalized features
  __shared__ float att[Kn * Dn];   // after wv projection
  __shared__ float hbuf[Kn * 64];  // MLP hidden
  const int b = blockIdx.x, t = threadIdx.x;
  for (int i = t; i < Kn * Dn; i += 256) {
    int k = i >> 7, e = i & 127;
    af[i] = fn_g[e] * (ws[OFF_DOTS + (size_t)b * Kn * Dn + i] -
                       ws[OFF_C + (size_t)b * Kn + k]) + fn_b[e];
  }
  __syncthreads();
  for (int i = t; i < Kn * Dn; i += 256) {
    int k = i >> 7, d2 = i & 127;
    const float* wr = wv + (size_t)d2 * Dn;
    float s = bv[d2];
    for (int e = 0; e < Dn; ++e) s += wr[e] * af[(k << 7) + e];
    att[i] = s;
  }
  __syncthreads();
  for (int i = t; i < Kn * 64; i += 256) {
    int k = i >> 6, j = i & 63;
    const float* sr = sw1 + (size_t)j * (Dn + 1);
    float s = sb1[j];
    for (int e = 0; e < Dn; ++e) s += sr[e] * att[(k << 7) + e];
    s += ws[OFF_ENT + (size_t)b * Kn + k] * sr[Dn];
    // exact GELU: x * (erf(x/sqrt(2)) + 1) / 2
    hbuf[i] = s * (erff(s / 1.41421356237309515f) + 1.0f) * 0.5f;
  }
  __syncthreads();
  if (t < Kn) {
    float s = sb2[0];
    for (int j = 0; j < 64; ++j) s += hbuf[(t << 6) + j] * sw2[j];
    out[OUT_STOP + (size_t)b * Kn + t] = s;
  }
}

// ---------------- launch ----------------
extern "C" void kernel_launch(void* const* d_in, const int* in_sizes, int n_in,
                              void* d_out, int out_size, void* d_ws, size_t ws_size,
                              hipStream_t stream) {
  (void)in_sizes; (void)n_in; (void)out_size; (void)ws_size;
  const float* features = (const float*)d_in[0];
  const float* clue     = (const float*)d_in[1];
  const float* wq       = (const float*)d_in[2];
  const float* bq       = (const float*)d_in[3];
  const float* wk       = (const float*)d_in[4];
  const float* bk       = (const float*)d_in[5];
  const float* wv       = (const float*)d_in[6];
  const float* bv       = (const float*)d_in[7];
  const float* sw1      = (const float*)d_in[8];
  const float* sb1      = (const float*)d_in[9];
  const float* sw2      = (const float*)d_in[10];
  const float* sb2      = (const float*)d_in[11];
  const float* qn_g     = (const float*)d_in[12];
  const float* qn_b     = (const float*)d_in[13];
  const float* fn_g     = (const float*)d_in[14];
  const float* fn_b     = (const float*)d_in[15];
  float* ws  = (float*)d_ws;
  float* out = (float*)d_out;

  // fold_in(key(42), k) on host: key(42) == [0, 42]; fold data == [0, k];
  // new key = full threefry output pair (unchanged by partitionable flag).
  FoldedKeys fk;
  for (int k = 0; k < Kn; ++k) {
    uint32_t x0 = 0u, x1 = (uint32_t)k;
    threefry2x32(0u, 42u, x0, x1);
    fk.k1[k] = x0; fk.k2[k] = x1;
  }

  hipLaunchKernelGGL(k_prep, dim3(Kn), dim3(128), 0, stream,
                     clue, wq, bq, wk, bk, qn_g, qn_b, fn_g, fn_b, ws);
  hipLaunchKernelGGL(k_base, dim3(4, Bn), dim3(256), 0, stream, features, ws, out);
  hipLaunchKernelGGL(k_loop, dim3(Bn), dim3(256), 0, stream, ws, out, fk);
  hipLaunchKernelGGL(k_dots, dim3(4, Bn), dim3(256), 0, stream, features, ws, out);
  hipLaunchKernelGGL(k_finish, dim3(Bn), dim3(256), 0, stream,
                     ws, wv, bv, sw1, sb1, sw2, sb2, fn_g, fn_b, out);
}

// Round 4
// 164.145 us; speedup vs baseline: 1.5204x; 1.0249x over previous
//
#include <hip/hip_runtime.h>
#include <stdint.h>
#include <math.h>

// ---------------- problem constants ----------------
namespace {
constexpr int Bn = 512, Dn = 128, Wn = 30, Kn = 5;
constexpr int HWn = 900;   // 30*30
constexpr int TQ  = 225;   // float4 pixel-quads per image

// workspace float offsets (total ~9.3 MB)
constexpr size_t OFF_A   = 0;                           // Kn*Dn = 640
constexpr size_t OFF_SA  = OFF_A + (size_t)Kn * Dn;     // 5 (pad 8)
constexpr size_t OFF_C0  = OFF_SA + 8;                  // 5 (pad 8)
constexpr size_t OFF_C   = OFF_C0 + 8;                  // Bn*Kn
constexpr size_t OFF_ENT = OFF_C + (size_t)Bn * Kn;     // Bn*Kn
constexpr size_t OFF_W   = OFF_ENT + (size_t)Bn * Kn;   // Bn*Kn*HWn (16B-aligned: 5776%4==0)

// output float offsets (centroids, attention_maps, stop_logits concatenated)
constexpr size_t OUT_CENT = 0;
constexpr size_t OUT_ATTN = (size_t)Bn * Kn * 2;               // 5120
constexpr size_t OUT_STOP = OUT_ATTN + (size_t)Bn * Kn * HWn;  // 2309120
}  // namespace

struct FoldedKeys { uint32_t k1[5]; uint32_t k2[5]; };

// ---------------- threefry2x32 (JAX partitionable, 20 rounds) ----------------
__host__ __device__ static inline uint32_t rotl32(uint32_t x, int d) {
  return (x << d) | (x >> (32 - d));
}

__host__ __device__ static inline void threefry2x32(uint32_t k1, uint32_t k2,
                                                    uint32_t& x0, uint32_t& x1) {
  uint32_t k3 = k1 ^ k2 ^ 0x1BD11BDAu;
  x0 += k1; x1 += k2;
#define TF_R(rot) { x0 += x1; x1 = rotl32(x1, rot); x1 ^= x0; }
  TF_R(13) TF_R(15) TF_R(26) TF_R(6)   x0 += k2; x1 += k3 + 1u;
  TF_R(17) TF_R(29) TF_R(16) TF_R(24)  x0 += k3; x1 += k1 + 2u;
  TF_R(13) TF_R(15) TF_R(26) TF_R(6)   x0 += k1; x1 += k2 + 3u;
  TF_R(17) TF_R(29) TF_R(16) TF_R(24)  x0 += k2; x1 += k3 + 4u;
  TF_R(13) TF_R(15) TF_R(26) TF_R(6)   x0 += k3; x1 += k1 + 5u;
#undef TF_R
}

// ---------------- reduction helpers ----------------
__device__ static inline float wsum(float v) {
#pragma unroll
  for (int o = 32; o; o >>= 1) v += __shfl_xor(v, o, 64);
  return v;
}
__device__ static inline float wmaxr(float v) {
#pragma unroll
  for (int o = 32; o; o >>= 1) v = fmaxf(v, __shfl_xor(v, o, 64));
  return v;
}
__device__ static inline float bsum4(float v, float* scr) {  // 256-thread block
  v = wsum(v);
  if ((threadIdx.x & 63) == 0) scr[threadIdx.x >> 6] = v;
  __syncthreads();
  float r = scr[0] + scr[1] + scr[2] + scr[3];
  __syncthreads();
  return r;
}
__device__ static inline float bmax4(float v, float* scr) {
  v = wmaxr(v);
  if ((threadIdx.x & 63) == 0) scr[threadIdx.x >> 6] = v;
  __syncthreads();
  float r = fmaxf(fmaxf(scr[0], scr[1]), fmaxf(scr[2], scr[3]));
  __syncthreads();
  return r;
}
__device__ static inline float bsum2(float v, float* scr) {  // 128-thread block
  v = wsum(v);
  if ((threadIdx.x & 63) == 0) scr[threadIdx.x >> 6] = v;
  __syncthreads();
  float r = scr[0] + scr[1];
  __syncthreads();
  return r;
}

// ---------------- kernel 0: per-query constants ----------------
// q = LN(clue)@wq.T+bq ; qk = q@wk ; A = fn_g*qk ; SA = sum A ; C0 = fn_b.qk + q.bk
__global__ __launch_bounds__(128) void k_prep(
    const float* __restrict__ clue, const float* __restrict__ wq,
    const float* __restrict__ bq, const float* __restrict__ wk,
    const float* __restrict__ bk, const float* __restrict__ qn_g,
    const float* __restrict__ qn_b, const float* __restrict__ fn_g,
    const float* __restrict__ fn_b, float* __restrict__ ws) {
  __shared__ float scr[2];
  __shared__ float lnc[Dn], qrow[Dn], qkrow[Dn];
  const int k = blockIdx.x, t = threadIdx.x;
  float xv = clue[(size_t)k * Dn + t];
  float m = bsum2(xv, scr) * (1.0f / Dn);
  float dd = xv - m;
  float var = bsum2(dd * dd, scr) * (1.0f / Dn);
  float r = 1.0f / sqrtf(var + 1e-5f);
  lnc[t] = dd * r * qn_g[t] + qn_b[t];
  __syncthreads();
  {
    float acc = bq[t];
    const float* wr = wq + (size_t)t * Dn;
    for (int e = 0; e < Dn; ++e) acc += lnc[e] * wr[e];
    qrow[t] = acc;
  }
  __syncthreads();
  {
    float acc = 0.f;
    for (int d = 0; d < Dn; ++d) acc += qrow[d] * wk[(size_t)d * Dn + t];
    qkrow[t] = acc;
    ws[OFF_A + (size_t)k * Dn + t] = fn_g[t] * acc;
  }
  __syncthreads();
  float sa = bsum2(fn_g[t] * qkrow[t], scr);
  float c0 = bsum2(fn_b[t] * qkrow[t] + qrow[t] * bk[t], scr);
  if (t == 0) {
    ws[OFF_SA + k] = sa;
    ws[OFF_C0 + k] = c0;
  }
}

// ---------------- kernel 1: fused LN-stats + base + gumbel-softmax loop -----
// one block per batch image b. Phase A: stream features (float4), per-pixel
// LN stats + 5 query dots held in registers. Phase B: 5 sequential
// gumbel-softmax steps with block reductions; writes attn (out) and
// w = attn*rstd (ws) as float4 stores.
__global__ __launch_bounds__(256) void k_main(const float* __restrict__ x,
                                              float* __restrict__ ws,
                                              float* __restrict__ out,
                                              FoldedKeys keys) {
  __shared__ float Al[Kn * Dn];
  __shared__ float scr4[4];
  __shared__ float scr16[16];
  const int b = blockIdx.x, t = threadIdx.x;
  for (int i = t; i < Kn * Dn; i += 256) Al[i] = ws[OFF_A + i];
  __syncthreads();
  const bool act = (t < TQ);

  // ---- phase A: stream this image's features once (1.84 MB, float4) ----
  float sm[4] = {0, 0, 0, 0}, sq[4] = {0, 0, 0, 0};
  float sd[5][4] = {};
  {
    const float* xb = x + (size_t)b * Dn * HWn + (act ? 4 * t : 0);
#pragma unroll 4
    for (int e = 0; e < Dn; ++e) {
      float4 v = *(const float4*)(xb + (size_t)e * HWn);
      float a0 = Al[e], a1 = Al[Dn + e], a2 = Al[2 * Dn + e],
            a3 = Al[3 * Dn + e], a4 = Al[4 * Dn + e];
      float vv[4] = {v.x, v.y, v.z, v.w};
#pragma unroll
      for (int c = 0; c < 4; ++c) {
        sm[c] += vv[c];
        sq[c] += vv[c] * vv[c];
        sd[0][c] += vv[c] * a0; sd[1][c] += vv[c] * a1; sd[2][c] += vv[c] * a2;
        sd[3][c] += vv[c] * a3; sd[4][c] += vv[c] * a4;
      }
    }
  }
  float SA[5], C0[5];
#pragma unroll
  for (int k = 0; k < 5; ++k) { SA[k] = ws[OFF_SA + k]; C0[k] = ws[OFF_C0 + k]; }
  float r[4], mr[4], base[5][4], cum[4], rw[4], cl[4];
#pragma unroll
  for (int c = 0; c < 4; ++c) {
    float m = sm[c] * (1.0f / Dn);
    float var = sq[c] * (1.0f / Dn) - m * m;
    r[c] = 1.0f / sqrtf(var + 1e-5f);
    mr[c] = m * r[c];
    cum[c] = 1.0f;
    int n = 4 * t + c;
    rw[c] = (float)(n / Wn);
    cl[c] = (float)(n % Wn);
#pragma unroll
    for (int k = 0; k < 5; ++k)
      base[k][c] = (r[c] * (sd[k][c] - m * SA[k]) + C0[k]) * 0.08838834764831844f;
  }

  // ---- phase B: 5 sequential gumbel-softmax steps ----
  for (int k = 0; k < 5; ++k) {
    const uint32_t fk1 = keys.k1[k], fk2 = keys.k2[k];
    float noisy[4];
#pragma unroll
    for (int c = 0; c < 4; ++c) {
      if (act) {
        float s = base[k][c] + logf(cum[c]);
        s = fminf(fmaxf(s, -50.f), 50.f);
        uint32_t j = (uint32_t)(b * HWn + 4 * t + c);
        uint32_t x0 = 0u, x1 = j;  // partitionable counter = (0, j)
        threefry2x32(fk1, fk2, x0, x1);
        uint32_t bits = x0 ^ x1;
        float u = __uint_as_float((bits >> 9) | 0x3f800000u) - 1.0f;
        u = fmaxf(u, 1e-10f);
        float g = -logf(-logf(u));
        noisy[c] = fminf(fmaxf(s + g, -50.f), 50.f);
      } else {
        noisy[c] = -1e30f;
      }
    }
    float lm = fmaxf(fmaxf(noisy[0], noisy[1]), fmaxf(noisy[2], noisy[3]));
    const float M = bmax4(lm, scr4);
    float p[4], ls = 0.f;
#pragma unroll
    for (int c = 0; c < 4; ++c) {
      p[c] = act ? expf(noisy[c] - M) : 0.f;
      ls += p[c];
    }
    const float Z = bsum4(ls, scr4);
    const float inv = 1.0f / Z;
    float red[4] = {0, 0, 0, 0};  // cr, cc, ea, ca
    float av[4];
#pragma unroll
    for (int c = 0; c < 4; ++c) {
      float a = p[c] * inv;
      av[c] = a;
      if (act) {
        red[0] += a * rw[c];
        red[1] += a * cl[c];
        float ac = fmaxf(a, 1e-10f);
        red[2] += ac * logf(ac);
        red[3] += a * mr[c];
        cum[c] = fmaxf(cum[c] * (1.0f - 0.9f * a), 1e-6f);
      }
    }
    if (act) {
      *(float4*)&out[OUT_ATTN + ((size_t)(b * Kn + k)) * HWn + 4 * t] =
          make_float4(av[0], av[1], av[2], av[3]);
      *(float4*)&ws[OFF_W + ((size_t)(b * Kn + k)) * HWn + 4 * t] =
          make_float4(av[0] * r[0], av[1] * r[1], av[2] * r[2], av[3] * r[3]);
    }
#pragma unroll
    for (int j2 = 0; j2 < 4; ++j2) red[j2] = wsum(red[j2]);
    if ((t & 63) == 0) {
      int w = t >> 6;
      scr16[w * 4 + 0] = red[0]; scr16[w * 4 + 1] = red[1];
      scr16[w * 4 + 2] = red[2]; scr16[w * 4 + 3] = red[3];
    }
    __syncthreads();
    if (t == 0) {
      float cr = scr16[0] + scr16[4] + scr16[8] + scr16[12];
      float cc = scr16[1] + scr16[5] + scr16[9] + scr16[13];
      float ea = scr16[2] + scr16[6] + scr16[10] + scr16[14];
      float ca = scr16[3] + scr16[7] + scr16[11] + scr16[15];
      out[OUT_CENT + ((size_t)(b * Kn + k)) * 2 + 0] = cr;
      out[OUT_CENT + ((size_t)(b * Kn + k)) * 2 + 1] = cc;
      ws[OFF_C + (size_t)b * Kn + k] = ca;
      ws[OFF_ENT + (size_t)b * Kn + k] = -ea / 6.802394763324311f;  // log(900)
    }
    __syncthreads();
  }
}

// ---------------- kernel 2: dots + LN-combine + wv proj + MLP + stop --------
// one block per b; features are L3-hot (just streamed by k_main).
__global__ __launch_bounds__(256) void k_tail(
    const float* __restrict__ x, const float* __restrict__ ws,
    const float* __restrict__ wv, const float* __restrict__ bv,
    const float* __restrict__ sw1, const float* __restrict__ sb1,
    const float* __restrict__ sw2, const float* __restrict__ sb2,
    const float* __restrict__ fn_g, const float* __restrict__ fn_b,
    float* __restrict__ out) {
  __shared__ float wl[Kn * HWn];   // 18 KB: w = attn*rstd for this b
  __shared__ float dots[Kn * Dn];
  __shared__ float af[Kn * Dn];
  __shared__ float att[Kn * Dn];
  __shared__ float hbuf[Kn * 64];
  const int b = blockIdx.x, t = threadIdx.x;
  {
    const float4* src = (const float4*)(ws + OFF_W + (size_t)b * Kn * HWn);
    float4* dst = (float4*)wl;
    for (int i = t; i < Kn * HWn / 4; i += 256) dst[i] = src[i];
  }
  __syncthreads();
  const int lane = t & 63, wid = t >> 6;
  const float4* xq = (const float4*)x + (size_t)b * (Dn * HWn / 4);
  for (int g = wid; g < Dn / 8; g += 4) {
    const int d0 = g * 8;
    float acc[8][5] = {};
    for (int i = lane; i < TQ; i += 64) {
      float w4[5][4];
#pragma unroll
      for (int k = 0; k < 5; ++k) {
        float4 wq = *(const float4*)&wl[k * HWn + 4 * i];
        w4[k][0] = wq.x; w4[k][1] = wq.y; w4[k][2] = wq.z; w4[k][3] = wq.w;
      }
#pragma unroll
      for (int j = 0; j < 8; ++j) {
        float4 v = xq[(size_t)(d0 + j) * TQ + i];
#pragma unroll
        for (int k = 0; k < 5; ++k)
          acc[j][k] += v.x * w4[k][0] + v.y * w4[k][1] +
                       v.z * w4[k][2] + v.w * w4[k][3];
      }
    }
#pragma unroll
    for (int j = 0; j < 8; ++j)
#pragma unroll
      for (int k = 0; k < 5; ++k) {
        float s = wsum(acc[j][k]);
        if (lane == 0) dots[k * Dn + d0 + j] = s;
      }
  }
  __syncthreads();
  for (int i = t; i < Kn * Dn; i += 256) {
    int k = i >> 7, e = i & 127;
    af[i] = fn_g[e] * (dots[i] - ws[OFF_C + (size_t)b * Kn + k]) + fn_b[e];
  }
  __syncthreads();
  for (int i = t; i < Kn * Dn; i += 256) {
    int k = i >> 7, d2 = i & 127;
    const float4* wr = (const float4*)(wv + (size_t)d2 * Dn);
    const float4* afq = (const float4*)&af[k << 7];
    float s = bv[d2];
    for (int e = 0; e < Dn / 4; ++e) {
      float4 a = afq[e], w = wr[e];
      s += a.x * w.x + a.y * w.y + a.z * w.z + a.w * w.w;
    }
    att[i] = s;
  }
  __syncthreads();
  for (int i = t; i < Kn * 64; i += 256) {
    int k = i >> 6, j = i & 63;
    const float* sr = sw1 + (size_t)j * (Dn + 1);
    float s = sb1[j];
    for (int e = 0; e < Dn; ++e) s += sr[e] * att[(k << 7) + e];
    s += ws[OFF_ENT + (size_t)b * Kn + k] * sr[Dn];
    // exact GELU: x * (erf(x/sqrt(2)) + 1) / 2
    hbuf[i] = s * (erff(s * 0.7071067811865475f) + 1.0f) * 0.5f;
  }
  __syncthreads();
  if (t < Kn) {
    float s = sb2[0];
    for (int j = 0; j < 64; ++j) s += hbuf[(t << 6) + j] * sw2[j];
    out[OUT_STOP + (size_t)b * Kn + t] = s;
  }
}

// ---------------- launch ----------------
extern "C" void kernel_launch(void* const* d_in, const int* in_sizes, int n_in,
                              void* d_out, int out_size, void* d_ws, size_t ws_size,
                              hipStream_t stream) {
  (void)in_sizes; (void)n_in; (void)out_size; (void)ws_size;
  const float* features = (const float*)d_in[0];
  const float* clue     = (const float*)d_in[1];
  const float* wq       = (const float*)d_in[2];
  const float* bq       = (const float*)d_in[3];
  const float* wk       = (const float*)d_in[4];
  const float* bk       = (const float*)d_in[5];
  const float* wv       = (const float*)d_in[6];
  const float* bv       = (const float*)d_in[7];
  const float* sw1      = (const float*)d_in[8];
  const float* sb1      = (const float*)d_in[9];
  const float* sw2      = (const float*)d_in[10];
  const float* sb2      = (const float*)d_in[11];
  const float* qn_g     = (const float*)d_in[12];
  const float* qn_b     = (const float*)d_in[13];
  const float* fn_g     = (const float*)d_in[14];
  const float* fn_b     = (const float*)d_in[15];
  float* ws  = (float*)d_ws;
  float* out = (float*)d_out;

  // fold_in(key(42), k) on host: full threefry of (0,k) with key (0,42).
  FoldedKeys fk;
  for (int k = 0; k < Kn; ++k) {
    uint32_t x0 = 0u, x1 = (uint32_t)k;
    threefry2x32(0u, 42u, x0, x1);
    fk.k1[k] = x0; fk.k2[k] = x1;
  }

  hipLaunchKernelGGL(k_prep, dim3(Kn), dim3(128), 0, stream,
                     clue, wq, bq, wk, bk, qn_g, qn_b, fn_g, fn_b, ws);
  hipLaunchKernelGGL(k_main, dim3(Bn), dim3(256), 0, stream,
                     features, ws, out, fk);
  hipLaunchKernelGGL(k_tail, dim3(Bn), dim3(256), 0, stream,
                     features, ws, wv, bv, sw1, sb1, sw2, sb2, fn_g, fn_b, out);
}

// Round 5
// 124.889 us; speedup vs baseline: 1.9982x; 1.3143x over previous
//
#include <hip/hip_runtime.h>
#include <stdint.h>
#include <math.h>

// ---------------- problem constants ----------------
namespace {
constexpr int Bn = 512, Dn = 128, Wn = 30, Kn = 5;
constexpr int HWn = 900;   // 30*30
constexpr int TQ  = 225;   // float4 pixel-quads per image

// workspace float offsets (tiny now: only per-query constants)
constexpr size_t OFF_A  = 0;                         // Kn*Dn = 640
constexpr size_t OFF_SA = OFF_A + (size_t)Kn * Dn;   // 5 (pad 8)
constexpr size_t OFF_C0 = OFF_SA + 8;                // 5 (pad 8)

// output float offsets (centroids, attention_maps, stop_logits concatenated)
constexpr size_t OUT_CENT = 0;
constexpr size_t OUT_ATTN = (size_t)Bn * Kn * 2;               // 5120
constexpr size_t OUT_STOP = OUT_ATTN + (size_t)Bn * Kn * HWn;  // 2309120
}  // namespace

struct FoldedKeys { uint32_t k1[5]; uint32_t k2[5]; };

// ---------------- threefry2x32 (JAX partitionable, 20 rounds) ----------------
__host__ __device__ static inline uint32_t rotl32(uint32_t x, int d) {
  return (x << d) | (x >> (32 - d));
}

__host__ __device__ static inline void threefry2x32(uint32_t k1, uint32_t k2,
                                                    uint32_t& x0, uint32_t& x1) {
  uint32_t k3 = k1 ^ k2 ^ 0x1BD11BDAu;
  x0 += k1; x1 += k2;
#define TF_R(rot) { x0 += x1; x1 = rotl32(x1, rot); x1 ^= x0; }
  TF_R(13) TF_R(15) TF_R(26) TF_R(6)   x0 += k2; x1 += k3 + 1u;
  TF_R(17) TF_R(29) TF_R(16) TF_R(24)  x0 += k3; x1 += k1 + 2u;
  TF_R(13) TF_R(15) TF_R(26) TF_R(6)   x0 += k1; x1 += k2 + 3u;
  TF_R(17) TF_R(29) TF_R(16) TF_R(24)  x0 += k2; x1 += k3 + 4u;
  TF_R(13) TF_R(15) TF_R(26) TF_R(6)   x0 += k3; x1 += k1 + 5u;
#undef TF_R
}

// ---------------- reduction helpers ----------------
__device__ static inline float wsum(float v) {
#pragma unroll
  for (int o = 32; o; o >>= 1) v += __shfl_xor(v, o, 64);
  return v;
}
__device__ static inline float wmaxr(float v) {
#pragma unroll
  for (int o = 32; o; o >>= 1) v = fmaxf(v, __shfl_xor(v, o, 64));
  return v;
}
__device__ static inline float bsum4(float v, float* scr) {  // 256-thread block
  v = wsum(v);
  if ((threadIdx.x & 63) == 0) scr[threadIdx.x >> 6] = v;
  __syncthreads();
  float r = scr[0] + scr[1] + scr[2] + scr[3];
  __syncthreads();
  return r;
}
__device__ static inline float bmax4(float v, float* scr) {
  v = wmaxr(v);
  if ((threadIdx.x & 63) == 0) scr[threadIdx.x >> 6] = v;
  __syncthreads();
  float r = fmaxf(fmaxf(scr[0], scr[1]), fmaxf(scr[2], scr[3]));
  __syncthreads();
  return r;
}
__device__ static inline float bsum2(float v, float* scr) {  // 128-thread block
  v = wsum(v);
  if ((threadIdx.x & 63) == 0) scr[threadIdx.x >> 6] = v;
  __syncthreads();
  float r = scr[0] + scr[1];
  __syncthreads();
  return r;
}

// ---------------- kernel 0: per-query constants ----------------
// q = LN(clue)@wq.T+bq ; qk = q@wk ; A = fn_g*qk ; SA = sum A ; C0 = fn_b.qk + q.bk
__global__ __launch_bounds__(128) void k_prep(
    const float* __restrict__ clue, const float* __restrict__ wq,
    const float* __restrict__ bq, const float* __restrict__ wk,
    const float* __restrict__ bk, const float* __restrict__ qn_g,
    const float* __restrict__ qn_b, const float* __restrict__ fn_g,
    const float* __restrict__ fn_b, float* __restrict__ ws) {
  __shared__ float scr[2];
  __shared__ float lnc[Dn], qrow[Dn], qkrow[Dn];
  const int k = blockIdx.x, t = threadIdx.x;
  float xv = clue[(size_t)k * Dn + t];
  float m = bsum2(xv, scr) * (1.0f / Dn);
  float dd = xv - m;
  float var = bsum2(dd * dd, scr) * (1.0f / Dn);
  float r = 1.0f / sqrtf(var + 1e-5f);
  lnc[t] = dd * r * qn_g[t] + qn_b[t];
  __syncthreads();
  {
    float acc = bq[t];
    const float* wr = wq + (size_t)t * Dn;
    for (int e = 0; e < Dn; ++e) acc += lnc[e] * wr[e];
    qrow[t] = acc;
  }
  __syncthreads();
  {
    float acc = 0.f;
    for (int d = 0; d < Dn; ++d) acc += qrow[d] * wk[(size_t)d * Dn + t];
    qkrow[t] = acc;
    ws[OFF_A + (size_t)k * Dn + t] = fn_g[t] * acc;
  }
  __syncthreads();
  float sa = bsum2(fn_g[t] * qkrow[t], scr);
  float c0 = bsum2(fn_b[t] * qkrow[t] + qrow[t] * bk[t], scr);
  if (t == 0) {
    ws[OFF_SA + k] = sa;
    ws[OFF_C0 + k] = c0;
  }
}

// ---------------- kernel 1: everything per image, fully fused ----------------
// Phase A: stream image (8-deep float4), LN stats + 5 base dots in registers.
// Phase B: 5 gumbel-softmax steps; attn->out, w=attn*rstd->LDS, C/ENT->LDS.
// Phase C: re-read image (reverse channel order, L3-hot) for attended dots.
// Phase D: LN-combine + wv projection + GELU MLP + stop logits.
__global__ __launch_bounds__(256) void k_all(
    const float* __restrict__ x, const float* __restrict__ ws,
    const float* __restrict__ wv, const float* __restrict__ bv,
    const float* __restrict__ sw1, const float* __restrict__ sb1,
    const float* __restrict__ sw2, const float* __restrict__ sb2,
    const float* __restrict__ fn_g, const float* __restrict__ fn_b,
    float* __restrict__ out, FoldedKeys keys) {
  __shared__ float Al[Kn * Dn];   // phase A: fn_g*qk ; phase D: reused as af
  __shared__ float wl[Kn * HWn];  // w = attn*rstd
  __shared__ float dots[Kn * Dn];
  __shared__ float att[Kn * Dn];
  __shared__ float hbuf[Kn * 64];
  __shared__ float scr4[4];
  __shared__ float scr16[16];
  __shared__ float caL[8], entL[8];
  const int b = blockIdx.x, t = threadIdx.x;
  for (int i = t; i < Kn * Dn; i += 256) Al[i] = ws[OFF_A + i];
  __syncthreads();
  const bool act = (t < TQ);
  const float4* xq = (const float4*)(x + (size_t)b * Dn * HWn);

  // ---- phase A: stream this image once (1.84 MB), 8 loads in flight ----
  float sm[4] = {0, 0, 0, 0}, sq[4] = {0, 0, 0, 0};
  float sd[5][4] = {};
  {
    const float4* xt = xq + (act ? t : 0);
    for (int e0 = 0; e0 < Dn; e0 += 8) {
      float4 vb[8];
#pragma unroll
      for (int j = 0; j < 8; ++j) vb[j] = xt[(size_t)(e0 + j) * TQ];
#pragma unroll
      for (int j = 0; j < 8; ++j) {
        const int e = e0 + j;
        float a0 = Al[e], a1 = Al[Dn + e], a2 = Al[2 * Dn + e],
              a3 = Al[3 * Dn + e], a4 = Al[4 * Dn + e];
        float vv[4] = {vb[j].x, vb[j].y, vb[j].z, vb[j].w};
#pragma unroll
        for (int c = 0; c < 4; ++c) {
          sm[c] += vv[c];
          sq[c] += vv[c] * vv[c];
          sd[0][c] += vv[c] * a0; sd[1][c] += vv[c] * a1;
          sd[2][c] += vv[c] * a2; sd[3][c] += vv[c] * a3;
          sd[4][c] += vv[c] * a4;
        }
      }
    }
  }
  float SA[5], C0[5];
#pragma unroll
  for (int k = 0; k < 5; ++k) { SA[k] = ws[OFF_SA + k]; C0[k] = ws[OFF_C0 + k]; }
  float r[4], mr[4], base[5][4], cum[4], rw[4], cl[4];
#pragma unroll
  for (int c = 0; c < 4; ++c) {
    float m = sm[c] * (1.0f / Dn);
    float var = sq[c] * (1.0f / Dn) - m * m;
    r[c] = 1.0f / sqrtf(var + 1e-5f);
    mr[c] = m * r[c];
    cum[c] = 1.0f;
    int n = 4 * t + c;
    rw[c] = (float)(n / Wn);
    cl[c] = (float)(n % Wn);
#pragma unroll
    for (int k = 0; k < 5; ++k)
      base[k][c] = (r[c] * (sd[k][c] - m * SA[k]) + C0[k]) * 0.08838834764831844f;
  }

  // ---- phase B: 5 sequential gumbel-softmax steps ----
  for (int k = 0; k < 5; ++k) {
    const uint32_t fk1 = keys.k1[k], fk2 = keys.k2[k];
    float noisy[4];
#pragma unroll
    for (int c = 0; c < 4; ++c) {
      if (act) {
        float s = base[k][c] + logf(cum[c]);
        s = fminf(fmaxf(s, -50.f), 50.f);
        uint32_t j = (uint32_t)(b * HWn + 4 * t + c);
        uint32_t x0 = 0u, x1 = j;  // partitionable counter = (0, j)
        threefry2x32(fk1, fk2, x0, x1);
        uint32_t bits = x0 ^ x1;
        float u = __uint_as_float((bits >> 9) | 0x3f800000u) - 1.0f;
        u = fmaxf(u, 1e-10f);
        float g = -logf(-logf(u));
        noisy[c] = fminf(fmaxf(s + g, -50.f), 50.f);
      } else {
        noisy[c] = -1e30f;
      }
    }
    float lm = fmaxf(fmaxf(noisy[0], noisy[1]), fmaxf(noisy[2], noisy[3]));
    const float M = bmax4(lm, scr4);
    float p[4], ls = 0.f;
#pragma unroll
    for (int c = 0; c < 4; ++c) {
      p[c] = act ? expf(noisy[c] - M) : 0.f;
      ls += p[c];
    }
    const float Z = bsum4(ls, scr4);
    const float inv = 1.0f / Z;
    float red[4] = {0, 0, 0, 0};  // cr, cc, ea, ca
    float av[4];
#pragma unroll
    for (int c = 0; c < 4; ++c) {
      float a = p[c] * inv;
      av[c] = a;
      if (act) {
        red[0] += a * rw[c];
        red[1] += a * cl[c];
        float ac = fmaxf(a, 1e-10f);
        red[2] += ac * logf(ac);
        red[3] += a * mr[c];
        cum[c] = fmaxf(cum[c] * (1.0f - 0.9f * a), 1e-6f);
      }
    }
    if (act) {
      *(float4*)&out[OUT_ATTN + ((size_t)(b * Kn + k)) * HWn + 4 * t] =
          make_float4(av[0], av[1], av[2], av[3]);
      *(float4*)&wl[(size_t)k * HWn + 4 * t] =
          make_float4(av[0] * r[0], av[1] * r[1], av[2] * r[2], av[3] * r[3]);
    }
#pragma unroll
    for (int j2 = 0; j2 < 4; ++j2) red[j2] = wsum(red[j2]);
    if ((t & 63) == 0) {
      int w = t >> 6;
      scr16[w * 4 + 0] = red[0]; scr16[w * 4 + 1] = red[1];
      scr16[w * 4 + 2] = red[2]; scr16[w * 4 + 3] = red[3];
    }
    __syncthreads();
    if (t == 0) {
      float cr = scr16[0] + scr16[4] + scr16[8] + scr16[12];
      float cc = scr16[1] + scr16[5] + scr16[9] + scr16[13];
      float ea = scr16[2] + scr16[6] + scr16[10] + scr16[14];
      float ca = scr16[3] + scr16[7] + scr16[11] + scr16[15];
      out[OUT_CENT + ((size_t)(b * Kn + k)) * 2 + 0] = cr;
      out[OUT_CENT + ((size_t)(b * Kn + k)) * 2 + 1] = cc;
      caL[k] = ca;
      entL[k] = -ea / 6.802394763324311f;  // log(900)
    }
    __syncthreads();
  }

  // ---- phase C: attended dots; re-read image in reverse channel order ----
  const int lane = t & 63, wid = t >> 6;
  for (int gi = 0; gi < 4; ++gi) {
    const int g = 15 - (gi * 4 + wid);  // descending channel groups
    const int d0 = g * 8;
    float acc[8][5] = {};
    for (int i0 = 0; i0 < 4; ++i0) {
      const int i = i0 * 64 + lane;
      if (i < TQ) {
        float4 v[8];
#pragma unroll
        for (int j = 0; j < 8; ++j) v[j] = xq[(size_t)(d0 + j) * TQ + i];
        float w4[5][4];
#pragma unroll
        for (int k = 0; k < 5; ++k) {
          float4 wv4 = *(const float4*)&wl[k * HWn + 4 * i];
          w4[k][0] = wv4.x; w4[k][1] = wv4.y; w4[k][2] = wv4.z; w4[k][3] = wv4.w;
        }
#pragma unroll
        for (int j = 0; j < 8; ++j)
#pragma unroll
          for (int k = 0; k < 5; ++k)
            acc[j][k] += v[j].x * w4[k][0] + v[j].y * w4[k][1] +
                         v[j].z * w4[k][2] + v[j].w * w4[k][3];
      }
    }
#pragma unroll
    for (int j = 0; j < 8; ++j)
#pragma unroll
      for (int k = 0; k < 5; ++k) {
        float s = wsum(acc[j][k]);
        if (lane == 0) dots[k * Dn + d0 + j] = s;
      }
  }
  __syncthreads();

  // ---- phase D: LN-combine + wv proj + MLP + stop ----
  float* af = Al;  // reuse (phase-A use of Al is long done)
  for (int i = t; i < Kn * Dn; i += 256) {
    int k = i >> 7, e = i & 127;
    af[i] = fn_g[e] * (dots[i] - caL[k]) + fn_b[e];
  }
  __syncthreads();
  for (int i = t; i < Kn * Dn; i += 256) {
    int k = i >> 7, d2 = i & 127;
    const float4* wr = (const float4*)(wv + (size_t)d2 * Dn);
    const float4* afq = (const float4*)&af[k << 7];
    float s = bv[d2];
    for (int e = 0; e < Dn / 4; ++e) {
      float4 a = afq[e], w = wr[e];
      s += a.x * w.x + a.y * w.y + a.z * w.z + a.w * w.w;
    }
    att[i] = s;
  }
  __syncthreads();
  for (int i = t; i < Kn * 64; i += 256) {
    int k = i >> 6, j = i & 63;
    const float* sr = sw1 + (size_t)j * (Dn + 1);
    float s = sb1[j];
    for (int e = 0; e < Dn; ++e) s += sr[e] * att[(k << 7) + e];
    s += entL[k] * sr[Dn];
    // exact GELU: x * (erf(x/sqrt(2)) + 1) / 2
    hbuf[i] = s * (erff(s * 0.7071067811865475f) + 1.0f) * 0.5f;
  }
  __syncthreads();
  if (t < Kn) {
    float s = sb2[0];
    for (int j = 0; j < 64; ++j) s += hbuf[(t << 6) + j] * sw2[j];
    out[OUT_STOP + (size_t)b * Kn + t] = s;
  }
}

// ---------------- launch ----------------
extern "C" void kernel_launch(void* const* d_in, const int* in_sizes, int n_in,
                              void* d_out, int out_size, void* d_ws, size_t ws_size,
                              hipStream_t stream) {
  (void)in_sizes; (void)n_in; (void)out_size; (void)ws_size;
  const float* features = (const float*)d_in[0];
  const float* clue     = (const float*)d_in[1];
  const float* wq       = (const float*)d_in[2];
  const float* bq       = (const float*)d_in[3];
  const float* wk       = (const float*)d_in[4];
  const float* bk       = (const float*)d_in[5];
  const float* wv       = (const float*)d_in[6];
  const float* bv       = (const float*)d_in[7];
  const float* sw1      = (const float*)d_in[8];
  const float* sb1      = (const float*)d_in[9];
  const float* sw2      = (const float*)d_in[10];
  const float* sb2      = (const float*)d_in[11];
  const float* qn_g     = (const float*)d_in[12];
  const float* qn_b     = (const float*)d_in[13];
  const float* fn_g     = (const float*)d_in[14];
  const float* fn_b     = (const float*)d_in[15];
  float* ws  = (float*)d_ws;
  float* out = (float*)d_out;

  // fold_in(key(42), k) on host: full threefry of (0,k) with key (0,42).
  FoldedKeys fk;
  for (int k = 0; k < Kn; ++k) {
    uint32_t x0 = 0u, x1 = (uint32_t)k;
    threefry2x32(0u, 42u, x0, x1);
    fk.k1[k] = x0; fk.k2[k] = x1;
  }

  hipLaunchKernelGGL(k_prep, dim3(Kn), dim3(128), 0, stream,
                     clue, wq, bq, wk, bk, qn_g, qn_b, fn_g, fn_b, ws);
  hipLaunchKernelGGL(k_all, dim3(Bn), dim3(256), 0, stream,
                     features, ws, wv, bv, sw1, sb1, sw2, sb2, fn_g, fn_b,
                     out, fk);
}